// Round 1
// baseline (634.669 us; speedup 1.0000x reference)
//
#include <hip/hip_runtime.h>

#define INF_  128
#define OUTF  256
#define LATF  128
#define OUT2  512
#define NEXP  8
#define OMEGA_ 30.0f

typedef float  f32x4  __attribute__((ext_vector_type(4)));
typedef __bf16 bf16x8 __attribute__((ext_vector_type(8)));

__device__ __forceinline__ unsigned short bfbits(float f) {
    // manual RNE f32 -> bf16 (inputs finite)
    unsigned int u = __builtin_bit_cast(unsigned int, f);
    return (unsigned short)((u + 0x7FFFu + ((u >> 16) & 1u)) >> 16);
}

// ---------------- weight transpose + bf16 convert ----------------
// Wt[e][n][k] = bf16(W[e][k][n]);  Wlt[e][n][k] = bf16(Wl[e][k][n])
__global__ void convw_kernel(const float* __restrict__ W, const float* __restrict__ Wl,
                             unsigned short* __restrict__ Wt, unsigned short* __restrict__ Wlt)
{
    const int t = blockIdx.x * 256 + threadIdx.x;
    if (t < NEXP * OUTF * INF_) {
        const int k = t & 127, n = (t >> 7) & 255, e = t >> 15;
        Wt[t] = bfbits(W[((size_t)e * 128 + k) * 256 + n]);
    } else {
        const int t2 = t - NEXP * OUTF * INF_;
        if (t2 < NEXP * OUT2 * LATF) {
            const int k = t2 & 127, n = (t2 >> 7) & 511, e = t2 >> 16;
            Wlt[t2] = bfbits(Wl[((size_t)e * 128 + k) * 512 + n]);
        }
    }
}

// ---------------- gating: logits, top-2, softmax, counts ----------------
__global__ void gate_kernel(const float* __restrict__ x,
                            const float* __restrict__ gw,
                            const float* __restrict__ gb,
                            unsigned short* __restrict__ eidx,
                            float2* __restrict__ gwt,
                            unsigned int* __restrict__ cnt)
{
    __shared__ float sgw[INF_ * NEXP];
    __shared__ int lc[16];
    const int tid = threadIdx.x;
    ((float4*)sgw)[tid] = ((const float4*)gw)[tid];   // 256 thr * 16B = 4KB
    if (tid < 16) lc[tid] = 0;
    __syncthreads();

    const int t = blockIdx.x * 256 + tid;
    float acc[8];
#pragma unroll
    for (int e = 0; e < 8; ++e) acc[e] = gb[e];
    const float4* xr = (const float4*)(x + (size_t)t * INF_);
#pragma unroll 8
    for (int i = 0; i < 32; ++i) {
        float4 v = xr[i];
#pragma unroll
        for (int j = 0; j < 4; ++j) {
            const float xk = (&v.x)[j];
            const float4 g0 = *(const float4*)&sgw[(i * 4 + j) * 8];
            const float4 g1 = *(const float4*)&sgw[(i * 4 + j) * 8 + 4];
            acc[0] += xk * g0.x; acc[1] += xk * g0.y; acc[2] += xk * g0.z; acc[3] += xk * g0.w;
            acc[4] += xk * g1.x; acc[5] += xk * g1.y; acc[6] += xk * g1.z; acc[7] += xk * g1.w;
        }
    }
    float best = -1e30f, sec = -1e30f; int bi = 0, si = 0;
#pragma unroll
    for (int e = 0; e < 8; ++e) {
        const float v = acc[e];
        if (v > best)      { sec = best; si = bi; best = v; bi = e; }
        else if (v > sec)  { sec = v; si = e; }
    }
    const float ew  = __expf(sec - best);
    const float inv = 1.0f / (1.0f + ew);
    eidx[t] = (unsigned short)(bi | (si << 8));
    gwt[t]  = make_float2(inv, ew * inv);
    atomicAdd(&lc[bi], 1);
    atomicAdd(&lc[8 + si], 1);
    __syncthreads();
    if (tid < 16) atomicAdd(&cnt[tid], (unsigned int)lc[tid]);
}

// ---------------- tiny scan: offs + cursors ----------------
__global__ void scan_kernel(unsigned int* c)   // [0..15]=cnt [16..31]=offs [32..47]=cursor
{
    if (threadIdx.x == 0) {
        unsigned int s = 0;
        for (int i = 0; i < 8; ++i)  { c[16 + i] = s; c[32 + i] = s; s += c[i]; }
        s = 0;
        for (int i = 8; i < 16; ++i) { c[16 + i] = s; c[32 + i] = s; s += c[i]; }
    }
}

// ---------------- scatter tokens into per-(slot,expert) lists ----------------
__global__ void scatter_kernel(const unsigned short* __restrict__ eidx,
                               const float2* __restrict__ gwt,
                               unsigned int* __restrict__ cur,
                               unsigned int* __restrict__ perm,
                               float* __restrict__ wlst,
                               int N)
{
    __shared__ int lc[16];
    __shared__ unsigned int lbase[16];
    const int tid = threadIdx.x;
    if (tid < 16) lc[tid] = 0;
    __syncthreads();
    const int t = blockIdx.x * 256 + tid;
    const unsigned short ee = eidx[t];
    const int e0 = ee & 255, e1 = ee >> 8;
    const float2 w = gwt[t];
    const int p0 = atomicAdd(&lc[e0], 1);
    const int p1 = atomicAdd(&lc[8 + e1], 1);
    __syncthreads();
    if (tid < 16) lbase[tid] = atomicAdd(&cur[tid], (unsigned int)lc[tid]);
    __syncthreads();
    const unsigned int q0 = lbase[e0] + p0;
    perm[q0] = t; wlst[q0] = w.x;
    const unsigned int q1 = lbase[8 + e1] + p1 + (unsigned int)N;
    perm[q1] = t; wlst[q1] = w.y;
}

// ---------------- grouped GEMM + fused sine epilogue ----------------
// tile: 128 gathered tokens x 768 cols (h:256 | scale:256 | shift:256), K=128
template<bool ACC>
__launch_bounds__(256, 2)
__global__ void moe_gemm_kernel(const float* __restrict__ x,
                                const float* __restrict__ lat,
                                const unsigned short* __restrict__ Wt,
                                const unsigned short* __restrict__ Wlt,
                                const float* __restrict__ bias,
                                const float* __restrict__ biasl,
                                const unsigned int* __restrict__ cnt,
                                const unsigned int* __restrict__ offs,
                                const unsigned int* __restrict__ perm,
                                const float* __restrict__ wlst,
                                float* __restrict__ out,
                                int slot, int N)
{
    __shared__ unsigned short sX[128 * 128];   // 32KB, bf16 bits, XOR-swizzled
    __shared__ unsigned short sL[128 * 128];   // 32KB

    const int e    = blockIdx.x;
    const int tile = blockIdx.y;
    const unsigned int c = cnt[slot * 8 + e];
    if ((unsigned int)(tile * 128) >= c) return;
    const unsigned int off = offs[slot * 8 + e] + (unsigned int)tile * 128;
    const int rows = min(128, (int)(c - (unsigned int)tile * 128));
    const unsigned int* permS = perm + (size_t)slot * N + off;
    const float* wS = wlst + (size_t)slot * N + off;

    const int tid  = threadIdx.x;
    const int lane = tid & 63;
    const int wv   = tid >> 6;
    const int wm   = wv >> 1, wn = wv & 1;

    // ---- stage gathered A tiles (x, latents) as bf16 into LDS ----
    {
        const int r = tid >> 1, half = tid & 1;
        const int tok = (int)permS[min(r, rows - 1)];
        const float4* xr = (const float4*)(x   + (size_t)tok * INF_) + half * 16;
        const float4* lr = (const float4*)(lat + (size_t)tok * LATF) + half * 16;
        const int swz = (r & 7) << 3;
        unsigned short* dX = &sX[r * 128];
        unsigned short* dL = &sL[r * 128];
#pragma unroll
        for (int i = 0; i < 16; ++i) {
            float4 v = xr[i];
            ushort4 u;
            u.x = bfbits(v.x); u.y = bfbits(v.y); u.z = bfbits(v.z); u.w = bfbits(v.w);
            const int uo = half * 64 + i * 4;
            *(ushort4*)&dX[uo ^ swz] = u;
            float4 v2 = lr[i];
            ushort4 u2;
            u2.x = bfbits(v2.x); u2.y = bfbits(v2.y); u2.z = bfbits(v2.z); u2.w = bfbits(v2.w);
            *(ushort4*)&dL[uo ^ swz] = u2;
        }
    }
    __syncthreads();

    const unsigned short* WtE  = Wt  + (size_t)e * OUTF * 128;
    const unsigned short* WltE = Wlt + (size_t)e * OUT2 * 128;
    const float* bE  = bias  + e * OUTF;
    const float* blE = biasl + e * OUT2;

    const int lrow = lane & 15;
    const int lgrp = lane >> 4;

#pragma unroll 1
    for (int nc = 0; nc < 4; ++nc) {           // 4 chunks of 64 output cols
        f32x4 hA[4][2], sA[4][2], fA[4][2];
#pragma unroll
        for (int mf = 0; mf < 4; ++mf)
#pragma unroll
            for (int nf = 0; nf < 2; ++nf) {
                hA[mf][nf] = (f32x4)0.0f; sA[mf][nf] = (f32x4)0.0f; fA[mf][nf] = (f32x4)0.0f;
            }

#pragma unroll
        for (int ks = 0; ks < 4; ++ks) {       // K = 4 x 32
            const int kb = ks * 32 + lgrp * 8;
            bf16x8 ax[4], al[4];
#pragma unroll
            for (int mf = 0; mf < 4; ++mf) {
                const int row = wm * 64 + mf * 16 + lrow;
                const int idx = row * 128 + (kb ^ ((row & 7) << 3));
                ax[mf] = *(const bf16x8*)&sX[idx];
                al[mf] = *(const bf16x8*)&sL[idx];
            }
#pragma unroll
            for (int nf = 0; nf < 2; ++nf) {
                const int n = nc * 64 + wn * 32 + nf * 16 + lrow;
                bf16x8 bw = *(const bf16x8*)&WtE [(size_t)n * 128 + kb];
                bf16x8 bs = *(const bf16x8*)&WltE[(size_t)n * 128 + kb];
                bf16x8 bh = *(const bf16x8*)&WltE[(size_t)(n + 256) * 128 + kb];
#pragma unroll
                for (int mf = 0; mf < 4; ++mf) {
                    hA[mf][nf] = __builtin_amdgcn_mfma_f32_16x16x32_bf16(ax[mf], bw, hA[mf][nf], 0, 0, 0);
                    sA[mf][nf] = __builtin_amdgcn_mfma_f32_16x16x32_bf16(al[mf], bs, sA[mf][nf], 0, 0, 0);
                    fA[mf][nf] = __builtin_amdgcn_mfma_f32_16x16x32_bf16(al[mf], bh, fA[mf][nf], 0, 0, 0);
                }
            }
        }

        // ---- fused epilogue: out(+)= w * sin(30*h*scale + shift) ----
#pragma unroll
        for (int mf = 0; mf < 4; ++mf) {
#pragma unroll
            for (int rr = 0; rr < 4; ++rr) {
                const int row = wm * 64 + mf * 16 + lgrp * 4 + rr;
                if (row < rows) {
                    const int tok = (int)permS[row];
                    const float wgt = wS[row];
                    float* orow = out + (size_t)tok * OUTF;
#pragma unroll
                    for (int nf = 0; nf < 2; ++nf) {
                        const int col = nc * 64 + wn * 32 + nf * 16 + lrow;
                        const float hv = hA[mf][nf][rr] + bE[col];
                        const float sc = sA[mf][nf][rr] + blE[col];
                        const float sh = fA[mf][nf][rr] + blE[256 + col];
                        const float val = wgt * __sinf(OMEGA_ * hv * sc + sh);
                        if (ACC) orow[col] += val; else orow[col] = val;
                    }
                }
            }
        }
    }
}

extern "C" void kernel_launch(void* const* d_in, const int* in_sizes, int n_in,
                              void* d_out, int out_size, void* d_ws, size_t ws_size,
                              hipStream_t stream)
{
    const float* x   = (const float*)d_in[0];
    const float* lat = (const float*)d_in[1];
    const float* gw  = (const float*)d_in[2];
    const float* gb  = (const float*)d_in[3];
    const float* W   = (const float*)d_in[4];
    const float* b   = (const float*)d_in[5];
    const float* Wl  = (const float*)d_in[6];
    const float* bl  = (const float*)d_in[7];
    float* out = (float*)d_out;
    const int N = in_sizes[0] / INF_;   // 131072

    char* ws = (char*)d_ws;
    unsigned int*   cnt  = (unsigned int*)ws;                        // [0..15]cnt [16..31]offs [32..47]cur
    unsigned short* eidx = (unsigned short*)(ws + 256);              // N
    float2*         gwt  = (float2*)(ws + 256 + 2 * (size_t)N);      // N
    unsigned int*   perm = (unsigned int*)(ws + 256 + 10 * (size_t)N); // 2N
    float*          wlst = (float*)(ws + 256 + 18 * (size_t)N);      // 2N
    unsigned short* Wt   = (unsigned short*)(ws + 256 + 26 * (size_t)N);
    unsigned short* Wlt  = Wt + NEXP * OUTF * INF_;

    hipMemsetAsync(cnt, 0, 64, stream);
    // latents passthrough output
    hipMemcpyAsync(out + (size_t)N * OUTF, lat, (size_t)N * LATF * sizeof(float),
                   hipMemcpyDeviceToDevice, stream);

    convw_kernel<<<dim3((NEXP * OUTF * INF_ + NEXP * OUT2 * LATF) / 256), 256, 0, stream>>>(W, Wl, Wt, Wlt);
    gate_kernel<<<dim3(N / 256), 256, 0, stream>>>(x, gw, gb, eidx, gwt, cnt);
    scan_kernel<<<1, 64, 0, stream>>>(cnt);
    scatter_kernel<<<dim3(N / 256), 256, 0, stream>>>(eidx, gwt, cnt + 32, perm, wlst, N);

    const dim3 ggrid(NEXP, (N + 127) / 128);
    moe_gemm_kernel<false><<<ggrid, 256, 0, stream>>>(x, lat, Wt, Wlt, b, bl,
                                                      cnt, cnt + 16, perm, wlst, out, 0, N);
    moe_gemm_kernel<true ><<<ggrid, 256, 0, stream>>>(x, lat, Wt, Wlt, b, bl,
                                                      cnt, cnt + 16, perm, wlst, out, 1, N);
}

// Round 3
// 288.893 us; speedup vs baseline: 2.1969x; 2.1969x over previous
//
#include <hip/hip_runtime.h>

#define INF_  128
#define OUTF  256
#define LATF  128
#define OUT2  512
#define NEXP  8
#define OMEGA_ 30.0f

typedef float  f32x4  __attribute__((ext_vector_type(4)));
typedef __bf16 bf16x8 __attribute__((ext_vector_type(8)));
typedef unsigned short ushort8 __attribute__((ext_vector_type(8)));

#define PACK_THREADS (NEXP * 4 * 4 * 3 * 4 * 64)   // 98304 -> 384 blocks of 256

__device__ __forceinline__ unsigned short bfbits(float f) {
    unsigned int u = __builtin_bit_cast(unsigned int, f);
    return (unsigned short)((u + 0x7FFFu + ((u >> 16) & 1u)) >> 16);
}

__device__ __forceinline__ bf16x8 cvt8(float4 a, float4 b) {
    bf16x8 r;
    r[0] = (__bf16)a.x; r[1] = (__bf16)a.y; r[2] = (__bf16)a.z; r[3] = (__bf16)a.w;
    r[4] = (__bf16)b.x; r[5] = (__bf16)b.y; r[6] = (__bf16)b.z; r[7] = (__bf16)b.w;
    return r;
}

// ---------------- weight pack: MFMA-fragment-ordered bf16 B ----------------
// Bpk ushort layout: ((((e*4+nc)*4+nf)*3+mat)*4+ks)*512 + lane*8 + j
// frag element: col = nc*64+nf*16+(lane&15), k = ks*32+(lane>>4)*8+j
// mat0 <- W[e][k][col]; mat1 <- Wl[e][k][col]; mat2 <- Wl[e][k][col+256]
__global__ void pack_kernel(const float* __restrict__ W, const float* __restrict__ Wl,
                            unsigned short* __restrict__ Bpk)
{
    const int t = blockIdx.x * 256 + threadIdx.x;
    if (t >= PACK_THREADS) return;
    const int l   = t & 63;
    const int ks  = (t >> 6) & 3;
    const int m3  = (t >> 8) % 3;
    const int g   = (t >> 8) / 3;
    const int nf  = g & 3, nc = (g >> 2) & 3, e = g >> 4;
    const int col = nc * 64 + nf * 16 + (l & 15);
    const int kb  = ks * 32 + (l >> 4) * 8;
    ushort8 o;
#pragma unroll
    for (int j = 0; j < 8; ++j) {
        float v;
        if (m3 == 0) v = W [((size_t)e * 128 + kb + j) * 256 + col];
        else         v = Wl[((size_t)e * 128 + kb + j) * 512 + col + (m3 == 2 ? 256 : 0)];
        o[j] = bfbits(v);
    }
    *(ushort8*)(Bpk + (size_t)t * 8) = o;
}

// ---------------- gating: logits, top-2, softmax, counts ----------------
__global__ void gate_kernel(const float* __restrict__ x,
                            const float* __restrict__ gw,
                            const float* __restrict__ gb,
                            unsigned short* __restrict__ eidx,
                            float2* __restrict__ gwt,
                            unsigned int* __restrict__ cnt)
{
    __shared__ float sgw[INF_ * NEXP];
    __shared__ int lc[16];
    const int tid = threadIdx.x;
    ((float4*)sgw)[tid] = ((const float4*)gw)[tid];
    if (tid < 16) lc[tid] = 0;
    __syncthreads();

    const int t = blockIdx.x * 256 + tid;
    float acc[8];
#pragma unroll
    for (int e = 0; e < 8; ++e) acc[e] = gb[e];
    const float4* xr = (const float4*)(x + (size_t)t * INF_);
#pragma unroll 8
    for (int i = 0; i < 32; ++i) {
        float4 v = xr[i];
#pragma unroll
        for (int j = 0; j < 4; ++j) {
            const float xk = (&v.x)[j];
            const float4 g0 = *(const float4*)&sgw[(i * 4 + j) * 8];
            const float4 g1 = *(const float4*)&sgw[(i * 4 + j) * 8 + 4];
            acc[0] += xk * g0.x; acc[1] += xk * g0.y; acc[2] += xk * g0.z; acc[3] += xk * g0.w;
            acc[4] += xk * g1.x; acc[5] += xk * g1.y; acc[6] += xk * g1.z; acc[7] += xk * g1.w;
        }
    }
    float best = -1e30f, sec = -1e30f; int bi = 0, si = 0;
#pragma unroll
    for (int e = 0; e < 8; ++e) {
        const float v = acc[e];
        if (v > best)      { sec = best; si = bi; best = v; bi = e; }
        else if (v > sec)  { sec = v; si = e; }
    }
    const float ew  = __expf(sec - best);
    const float inv = 1.0f / (1.0f + ew);
    eidx[t] = (unsigned short)(bi | (si << 8));
    gwt[t]  = make_float2(inv, ew * inv);
    atomicAdd(&lc[bi], 1);
    atomicAdd(&lc[8 + si], 1);
    __syncthreads();
    if (tid < 16) atomicAdd(&cnt[tid], (unsigned int)lc[tid]);
}

// ---------------- tiny scan: offs + cursors ----------------
__global__ void scan_kernel(unsigned int* c)   // [0..15]=cnt [16..31]=offs [32..47]=cursor
{
    if (threadIdx.x == 0) {
        unsigned int s = 0;
        for (int i = 0; i < 8; ++i)  { c[16 + i] = s; c[32 + i] = s; s += c[i]; }
        s = 0;
        for (int i = 8; i < 16; ++i) { c[16 + i] = s; c[32 + i] = s; s += c[i]; }
    }
}

// ---------------- scatter tokens into per-(slot,expert) lists ----------------
__global__ void scatter_kernel(const unsigned short* __restrict__ eidx,
                               const float2* __restrict__ gwt,
                               unsigned int* __restrict__ cur,
                               unsigned int* __restrict__ perm,
                               float* __restrict__ wlst,
                               int N)
{
    __shared__ int lc[16];
    __shared__ unsigned int lbase[16];
    const int tid = threadIdx.x;
    if (tid < 16) lc[tid] = 0;
    __syncthreads();
    const int t = blockIdx.x * 256 + tid;
    const unsigned short ee = eidx[t];
    const int e0 = ee & 255, e1 = ee >> 8;
    const float2 w = gwt[t];
    const int p0 = atomicAdd(&lc[e0], 1);
    const int p1 = atomicAdd(&lc[8 + e1], 1);
    __syncthreads();
    if (tid < 16) lbase[tid] = atomicAdd(&cur[tid], (unsigned int)lc[tid]);
    __syncthreads();
    const unsigned int q0 = lbase[e0] + p0;
    perm[q0] = t; wlst[q0] = w.x;
    const unsigned int q1 = lbase[8 + e1] + p1 + (unsigned int)N;
    perm[q1] = t; wlst[q1] = w.y;
}

// ---------------- grouped GEMM, LDS-free, fused sine epilogue ----------------
// block = 4 waves x 256 thr; tile M=128 tokens (wave owns 32 rows) x 256 cols (nc loop);
// A gathered straight into MFMA-layout registers (bf16); B fragments are
// coalesced 1KB wave-loads from the pre-packed, L2-resident Bpk.
template<bool ACC>
__launch_bounds__(256, 2)
__global__ void moe_gemm_kernel(const float* __restrict__ x,
                                const float* __restrict__ lat,
                                const unsigned short* __restrict__ Bpk,
                                const float* __restrict__ bias,
                                const float* __restrict__ biasl,
                                const unsigned int* __restrict__ cnt,
                                const unsigned int* __restrict__ offs,
                                const unsigned int* __restrict__ perm,
                                const float* __restrict__ wlst,
                                float* __restrict__ out,
                                int slot, int N)
{
    const int e    = blockIdx.x;
    const int tile = blockIdx.y;
    const unsigned int c = cnt[slot * 8 + e];
    if ((unsigned int)(tile * 128) >= c) return;
    const unsigned int off = offs[slot * 8 + e] + (unsigned int)tile * 128u;
    const int rows = min(128, (int)(c - (unsigned int)tile * 128u));
    const unsigned int* permS = perm + (size_t)slot * N + off;
    const float* wS = wlst + (size_t)slot * N + off;

    const int tid  = threadIdx.x;
    const int lane = tid & 63;
    const int w    = tid >> 6;           // wave owns rows w*32 .. w*32+31
    const int lrow = lane & 15;
    const int lgrp = lane >> 4;

    const int r0 = w * 32 + lrow, r1 = r0 + 16;
    const int t0 = (int)permS[min(r0, rows - 1)];
    const int t1 = (int)permS[min(r1, rows - 1)];

    // ---- A gather -> registers (MFMA layout), f32 -> bf16 ----
    bf16x8 ax[2][4], al[2][4];
    {
        const float* x0 = x   + (size_t)t0 * INF_;
        const float* x1 = x   + (size_t)t1 * INF_;
        const float* l0 = lat + (size_t)t0 * LATF;
        const float* l1 = lat + (size_t)t1 * LATF;
#pragma unroll
        for (int ks = 0; ks < 4; ++ks) {
            const int kb = ks * 32 + lgrp * 8;
            ax[0][ks] = cvt8(*(const float4*)(x0 + kb), *(const float4*)(x0 + kb + 4));
            ax[1][ks] = cvt8(*(const float4*)(x1 + kb), *(const float4*)(x1 + kb + 4));
            al[0][ks] = cvt8(*(const float4*)(l0 + kb), *(const float4*)(l0 + kb + 4));
            al[1][ks] = cvt8(*(const float4*)(l1 + kb), *(const float4*)(l1 + kb + 4));
        }
    }

    const unsigned short* Be  = Bpk + (size_t)e * (4 * 4 * 3 * 4 * 512);
    const float* bE  = bias  + e * OUTF;
    const float* blE = biasl + e * OUT2;

#pragma unroll
    for (int nc = 0; nc < 4; ++nc) {      // 4 chunks of 64 output cols
        f32x4 hA[2][4], sA[2][4], fA[2][4];
#pragma unroll
        for (int mf = 0; mf < 2; ++mf)
#pragma unroll
            for (int nf = 0; nf < 4; ++nf) {
                hA[mf][nf] = (f32x4)0.0f; sA[mf][nf] = (f32x4)0.0f; fA[mf][nf] = (f32x4)0.0f;
            }

        const unsigned short* Bnc = Be + nc * (4 * 3 * 4 * 512);
#pragma unroll
        for (int nf = 0; nf < 4; ++nf) {
            const unsigned short* Bf = Bnc + nf * (3 * 4 * 512) + lane * 8;
            bf16x8 bw[4], bs[4], bh[4];
#pragma unroll
            for (int ks = 0; ks < 4; ++ks) {
                bw[ks] = *(const bf16x8*)(Bf + (0 * 4 + ks) * 512);
                bs[ks] = *(const bf16x8*)(Bf + (1 * 4 + ks) * 512);
                bh[ks] = *(const bf16x8*)(Bf + (2 * 4 + ks) * 512);
            }
#pragma unroll
            for (int ks = 0; ks < 4; ++ks) {
#pragma unroll
                for (int mf = 0; mf < 2; ++mf) {
                    hA[mf][nf] = __builtin_amdgcn_mfma_f32_16x16x32_bf16(ax[mf][ks], bw[ks], hA[mf][nf], 0, 0, 0);
                    sA[mf][nf] = __builtin_amdgcn_mfma_f32_16x16x32_bf16(al[mf][ks], bs[ks], sA[mf][nf], 0, 0, 0);
                    fA[mf][nf] = __builtin_amdgcn_mfma_f32_16x16x32_bf16(al[mf][ks], bh[ks], fA[mf][nf], 0, 0, 0);
                }
            }
        }

        // ---- fused epilogue: out(+)= w * sin(30*h*scale + shift) ----
        float be[4], b1[4], b2[4];
#pragma unroll
        for (int nf = 0; nf < 4; ++nf) {
            const int col = nc * 64 + nf * 16 + lrow;
            be[nf] = bE[col]; b1[nf] = blE[col]; b2[nf] = blE[256 + col];
        }
#pragma unroll
        for (int mf = 0; mf < 2; ++mf)
#pragma unroll
        for (int rr = 0; rr < 4; ++rr) {
            const int row = w * 32 + mf * 16 + lgrp * 4 + rr;
            if (row < rows) {
                const int tok = (int)permS[row];
                const float wgt = wS[row];
                float* orow = out + (size_t)tok * OUTF;
#pragma unroll
                for (int nf = 0; nf < 4; ++nf) {
                    const int col = nc * 64 + nf * 16 + lrow;
                    const float hv = hA[mf][nf][rr] + be[nf];
                    const float sc = sA[mf][nf][rr] + b1[nf];
                    const float sh = fA[mf][nf][rr] + b2[nf];
                    const float val = wgt * __sinf(OMEGA_ * hv * sc + sh);
                    if (ACC) orow[col] += val; else orow[col] = val;
                }
            }
        }
    }
}

extern "C" void kernel_launch(void* const* d_in, const int* in_sizes, int n_in,
                              void* d_out, int out_size, void* d_ws, size_t ws_size,
                              hipStream_t stream)
{
    const float* x   = (const float*)d_in[0];
    const float* lat = (const float*)d_in[1];
    const float* gw  = (const float*)d_in[2];
    const float* gb  = (const float*)d_in[3];
    const float* W   = (const float*)d_in[4];
    const float* b   = (const float*)d_in[5];
    const float* Wl  = (const float*)d_in[6];
    const float* bl  = (const float*)d_in[7];
    float* out = (float*)d_out;
    const int N = in_sizes[0] / INF_;   // 131072

    char* ws = (char*)d_ws;
    unsigned int*   cnt  = (unsigned int*)ws;                          // [0..15]cnt [16..31]offs [32..47]cur
    unsigned short* eidx = (unsigned short*)(ws + 256);                // N
    float2*         gwt  = (float2*)(ws + 256 + 2 * (size_t)N);        // N
    unsigned int*   perm = (unsigned int*)(ws + 256 + 10 * (size_t)N); // 2N
    float*          wlst = (float*)(ws + 256 + 18 * (size_t)N);        // 2N
    unsigned short* Bpk  = (unsigned short*)(ws + 256 + 26 * (size_t)N); // 1.5MB

    hipMemsetAsync(cnt, 0, 64, stream);
    // latents passthrough output
    hipMemcpyAsync(out + (size_t)N * OUTF, lat, (size_t)N * LATF * sizeof(float),
                   hipMemcpyDeviceToDevice, stream);

    pack_kernel<<<dim3(PACK_THREADS / 256), 256, 0, stream>>>(W, Wl, Bpk);
    gate_kernel<<<dim3(N / 256), 256, 0, stream>>>(x, gw, gb, eidx, gwt, cnt);
    scan_kernel<<<1, 64, 0, stream>>>(cnt);
    scatter_kernel<<<dim3(N / 256), 256, 0, stream>>>(eidx, gwt, cnt + 32, perm, wlst, N);

    const dim3 ggrid(NEXP, (N + 127) / 128);
    moe_gemm_kernel<false><<<ggrid, 256, 0, stream>>>(x, lat, Bpk, b, bl,
                                                      cnt, cnt + 16, perm, wlst, out, 0, N);
    moe_gemm_kernel<true ><<<ggrid, 256, 0, stream>>>(x, lat, Bpk, b, bl,
                                                      cnt, cnt + 16, perm, wlst, out, 1, N);
}

// Round 5
// 226.589 us; speedup vs baseline: 2.8010x; 1.2750x over previous
//
#include <hip/hip_runtime.h>

#define INF_  128
#define OUTF  256
#define LATF  128
#define OUT2  512
#define NEXP  8
#define OMEGA_ 30.0f

typedef float  f32x4  __attribute__((ext_vector_type(4)));
typedef __bf16 bf16x8 __attribute__((ext_vector_type(8)));
typedef unsigned short ushort8 __attribute__((ext_vector_type(8)));

#define PACK_THREADS (NEXP * 4 * 4 * 3 * 4 * 64)   // 98304 -> 384 blocks of 256

__device__ __forceinline__ unsigned short bfbits(float f) {
    unsigned int u = __builtin_bit_cast(unsigned int, f);
    return (unsigned short)((u + 0x7FFFu + ((u >> 16) & 1u)) >> 16);
}

__device__ __forceinline__ bf16x8 cvt8(f32x4 a, f32x4 b) {
    bf16x8 r;
    r[0] = (__bf16)a.x; r[1] = (__bf16)a.y; r[2] = (__bf16)a.z; r[3] = (__bf16)a.w;
    r[4] = (__bf16)b.x; r[5] = (__bf16)b.y; r[6] = (__bf16)b.z; r[7] = (__bf16)b.w;
    return r;
}

// global -> LDS async, 16B per lane, linear dest
#define GLOAD_LDS16(g, l) __builtin_amdgcn_global_load_lds( \
    (const __attribute__((address_space(1))) unsigned int*)(g), \
    (__attribute__((address_space(3))) unsigned int*)(l), 16, 0, 0)

// ---------------- weight pack: MFMA-fragment-ordered bf16 B ----------------
// Bpk ushort layout: ((((e*4+nc)*4+nf)*3+mat)*4+ks)*512 + lane*8 + j
// frag element: col = nc*64+nf*16+(lane&15), k = ks*32+(lane>>4)*8+j
// mat0 <- W[e][k][col]; mat1 <- Wl[e][k][col]; mat2 <- Wl[e][k][col+256]
__global__ void pack_kernel(const float* __restrict__ W, const float* __restrict__ Wl,
                            unsigned short* __restrict__ Bpk)
{
    const int t = blockIdx.x * 256 + threadIdx.x;
    if (t >= PACK_THREADS) return;
    const int l   = t & 63;
    const int ks  = (t >> 6) & 3;
    const int m3  = (t >> 8) % 3;
    const int g   = (t >> 8) / 3;
    const int nf  = g & 3, nc = (g >> 2) & 3, e = g >> 4;
    const int col = nc * 64 + nf * 16 + (l & 15);
    const int kb  = ks * 32 + (l >> 4) * 8;
    ushort8 o;
#pragma unroll
    for (int j = 0; j < 8; ++j) {
        float v;
        if (m3 == 0) v = W [((size_t)e * 128 + kb + j) * 256 + col];
        else         v = Wl[((size_t)e * 128 + kb + j) * 512 + col + (m3 == 2 ? 256 : 0)];
        o[j] = bfbits(v);
    }
    *(ushort8*)(Bpk + (size_t)t * 8) = o;
}

// ---------------- gating: logits, top-2, softmax, counts, latents copy ----------------
__global__ void gate_kernel(const float* __restrict__ x,
                            const float* __restrict__ lat,
                            const float* __restrict__ gw,
                            const float* __restrict__ gb,
                            unsigned short* __restrict__ eidx,
                            float2* __restrict__ gwt,
                            unsigned int* __restrict__ cnt,
                            float* __restrict__ lat_out)
{
    __shared__ float sgw[INF_ * NEXP];
    __shared__ int lc[16];
    const int tid = threadIdx.x;
    ((float4*)sgw)[tid] = ((const float4*)gw)[tid];
    if (tid < 16) lc[tid] = 0;
    __syncthreads();

    const int t = blockIdx.x * 256 + tid;
    float acc[8];
#pragma unroll
    for (int e = 0; e < 8; ++e) acc[e] = gb[e];
    const float4* xr = (const float4*)(x + (size_t)t * INF_);
#pragma unroll 8
    for (int i = 0; i < 32; ++i) {
        float4 v = xr[i];
#pragma unroll
        for (int j = 0; j < 4; ++j) {
            const float xk = (&v.x)[j];
            const float4 g0 = *(const float4*)&sgw[(i * 4 + j) * 8];
            const float4 g1 = *(const float4*)&sgw[(i * 4 + j) * 8 + 4];
            acc[0] += xk * g0.x; acc[1] += xk * g0.y; acc[2] += xk * g0.z; acc[3] += xk * g0.w;
            acc[4] += xk * g1.x; acc[5] += xk * g1.y; acc[6] += xk * g1.z; acc[7] += xk * g1.w;
        }
    }
    float best = -1e30f, sec = -1e30f; int bi = 0, si = 0;
#pragma unroll
    for (int e = 0; e < 8; ++e) {
        const float v = acc[e];
        if (v > best)      { sec = best; si = bi; best = v; bi = e; }
        else if (v > sec)  { sec = v; si = e; }
    }
    const float ew  = __expf(sec - best);
    const float inv = 1.0f / (1.0f + ew);
    eidx[t] = (unsigned short)(bi | (si << 8));
    gwt[t]  = make_float2(inv, ew * inv);
    atomicAdd(&lc[bi], 1);
    atomicAdd(&lc[8 + si], 1);
    __syncthreads();
    if (tid < 16) atomicAdd(&cnt[tid], (unsigned int)lc[tid]);

    // latents passthrough (output 1), fused to avoid a separate 134MB memcpy
    const f32x4* lr = (const f32x4*)(lat) + (size_t)blockIdx.x * 8192;
    f32x4*       lo = (f32x4*)(lat_out)   + (size_t)blockIdx.x * 8192;
#pragma unroll
    for (int i = 0; i < 32; ++i) {
        f32x4 v = lr[tid + i * 256];
        __builtin_nontemporal_store(v, &lo[tid + i * 256]);
    }
}

// ---------------- tiny scan: offs + cursors ----------------
__global__ void scan_kernel(unsigned int* c)   // [0..15]=cnt [16..31]=offs [32..47]=cursor
{
    if (threadIdx.x == 0) {
        unsigned int s = 0;
        for (int i = 0; i < 8; ++i)  { c[16 + i] = s; c[32 + i] = s; s += c[i]; }
        s = 0;
        for (int i = 8; i < 16; ++i) { c[16 + i] = s; c[32 + i] = s; s += c[i]; }
    }
}

// ---------------- scatter tokens into per-(slot,expert) lists ----------------
__global__ void scatter_kernel(const unsigned short* __restrict__ eidx,
                               const float2* __restrict__ gwt,
                               unsigned int* __restrict__ cur,
                               unsigned int* __restrict__ perm,
                               float* __restrict__ wlst,
                               int N)
{
    __shared__ int lc[16];
    __shared__ unsigned int lbase[16];
    const int tid = threadIdx.x;
    if (tid < 16) lc[tid] = 0;
    __syncthreads();
    const int t = blockIdx.x * 256 + tid;
    const unsigned short ee = eidx[t];
    const int e0 = ee & 255, e1 = ee >> 8;
    const float2 w = gwt[t];
    const int p0 = atomicAdd(&lc[e0], 1);
    const int p1 = atomicAdd(&lc[8 + e1], 1);
    __syncthreads();
    if (tid < 16) lbase[tid] = atomicAdd(&cur[tid], (unsigned int)lc[tid]);
    __syncthreads();
    const unsigned int q0 = lbase[e0] + p0;
    perm[q0] = t; wlst[q0] = w.x;
    const unsigned int q1 = lbase[8 + e1] + p1 + (unsigned int)N;
    perm[q1] = t; wlst[q1] = w.y;
}

// ---------------- grouped GEMM: LDS-staged B, 8-phase dbuf, fused sine ----------------
// block = 4 waves, tile M=128 (wave owns 32 rows) x 256 cols; K=128.
// B staged per 64-col half-chunk (24KB) via global_load_lds, double buffered.
template<bool ACC>
__launch_bounds__(256, 2)
__global__ void moe_gemm_kernel(const float* __restrict__ x,
                                const float* __restrict__ lat,
                                const unsigned short* __restrict__ Bpk,
                                const float* __restrict__ bias,
                                const float* __restrict__ biasl,
                                const unsigned int* __restrict__ cnt,
                                const unsigned int* __restrict__ offs,
                                const unsigned int* __restrict__ perm,
                                const float* __restrict__ wlst,
                                float* __restrict__ out,
                                int slot, int N)
{
    __shared__ __align__(16) unsigned short sB[2][12288];   // 2 x 24KB

    const int e    = blockIdx.x;
    const int tile = blockIdx.y;
    const unsigned int c = cnt[slot * 8 + e];
    if ((unsigned int)(tile * 128) >= c) return;            // uniform exit, before any barrier
    const unsigned int off = offs[slot * 8 + e] + (unsigned int)tile * 128u;
    const int rows = min(128, (int)(c - (unsigned int)tile * 128u));
    const unsigned int* permS = perm + (size_t)slot * N + off;
    const float* wS = wlst + (size_t)slot * N + off;

    const int tid  = threadIdx.x;
    const int lane = tid & 63;
    const int w    = tid >> 6;           // wave owns rows w*32 .. w*32+31
    const int lrow = lane & 15;
    const int lgrp = lane >> 4;

    // ---- per-lane epilogue row metadata (8 rows per lane) ----
    int   tokq[2][4];
    float wgtq[2][4];
#pragma unroll
    for (int mf = 0; mf < 2; ++mf)
#pragma unroll
        for (int rr = 0; rr < 4; ++rr) {
            const int row = w * 32 + mf * 16 + lgrp * 4 + rr;
            const int cl  = min(row, rows - 1);
            tokq[mf][rr] = (int)permS[cl];
            wgtq[mf][rr] = wS[cl];
        }

    // ---- A gather -> registers (MFMA layout), f32 -> bf16 ----
    const int r0 = w * 32 + lrow, r1 = r0 + 16;
    const int t0 = (int)permS[min(r0, rows - 1)];
    const int t1 = (int)permS[min(r1, rows - 1)];
    bf16x8 ax[2][4], al[2][4];
    {
        const float* x0 = x   + (size_t)t0 * INF_;
        const float* x1 = x   + (size_t)t1 * INF_;
        const float* l0 = lat + (size_t)t0 * LATF;
        const float* l1 = lat + (size_t)t1 * LATF;
#pragma unroll
        for (int ks = 0; ks < 4; ++ks) {
            const int kb = ks * 32 + lgrp * 8;
            if (ACC) {   // second pass: last use of x/lat -> non-temporal
                ax[0][ks] = cvt8(__builtin_nontemporal_load((const f32x4*)(x0 + kb)),
                                 __builtin_nontemporal_load((const f32x4*)(x0 + kb + 4)));
                ax[1][ks] = cvt8(__builtin_nontemporal_load((const f32x4*)(x1 + kb)),
                                 __builtin_nontemporal_load((const f32x4*)(x1 + kb + 4)));
                al[0][ks] = cvt8(__builtin_nontemporal_load((const f32x4*)(l0 + kb)),
                                 __builtin_nontemporal_load((const f32x4*)(l0 + kb + 4)));
                al[1][ks] = cvt8(__builtin_nontemporal_load((const f32x4*)(l1 + kb)),
                                 __builtin_nontemporal_load((const f32x4*)(l1 + kb + 4)));
            } else {
                ax[0][ks] = cvt8(*(const f32x4*)(x0 + kb), *(const f32x4*)(x0 + kb + 4));
                ax[1][ks] = cvt8(*(const f32x4*)(x1 + kb), *(const f32x4*)(x1 + kb + 4));
                al[0][ks] = cvt8(*(const f32x4*)(l0 + kb), *(const f32x4*)(l0 + kb + 4));
                al[1][ks] = cvt8(*(const f32x4*)(l1 + kb), *(const f32x4*)(l1 + kb + 4));
            }
        }
    }

    const unsigned short* Bc = Bpk + (size_t)e * (4 * 4 * 3 * 4 * 512);
    const float* bE  = bias  + e * OUTF;
    const float* blE = biasl + e * OUT2;

    // ---- stage phase 0 ----
#pragma unroll
    for (int r = 0; r < 6; ++r) {
        GLOAD_LDS16(Bc + (size_t)(r * 256 + tid) * 8,
                    &sB[0][(size_t)(r * 256 + w * 64) * 8]);
    }
    __syncthreads();

    f32x4 hA[2][4], sA[2][4], fA[2][4];

#pragma unroll
    for (int p = 0; p < 8; ++p) {
        const int nc  = p >> 1;
        const int buf = p & 1;

        if ((p & 1) == 0) {
#pragma unroll
            for (int mf = 0; mf < 2; ++mf)
#pragma unroll
                for (int nf = 0; nf < 4; ++nf) {
                    hA[mf][nf] = (f32x4)0.0f; sA[mf][nf] = (f32x4)0.0f; fA[mf][nf] = (f32x4)0.0f;
                }
        }

        // stage next phase's 24KB into the other buffer
        if (p < 7) {
#pragma unroll
            for (int r = 0; r < 6; ++r) {
                GLOAD_LDS16(Bc + (size_t)(p + 1) * 12288 + (size_t)(r * 256 + tid) * 8,
                            &sB[(p + 1) & 1][(size_t)(r * 256 + w * 64) * 8]);
            }
        }

        // preload old out values for the RMW pass (hidden under the MFMAs)
        float oldv[2][4][4];
        if (ACC && (p & 1)) {
#pragma unroll
            for (int mf = 0; mf < 2; ++mf)
#pragma unroll
                for (int rr = 0; rr < 4; ++rr) {
                    const float* orow = out + (size_t)tokq[mf][rr] * OUTF;
#pragma unroll
                    for (int nf = 0; nf < 4; ++nf)
                        oldv[mf][rr][nf] = orow[nc * 64 + nf * 16 + lrow];
                }
        }

        // compute: 2 nf-groups x 3 mats x 4 ks x 2 mf = 48 MFMA
#pragma unroll
        for (int nf2 = 0; nf2 < 2; ++nf2) {
            const int nf = ((p & 1) << 1) + nf2;
            bf16x8 bw[4], bs[4], bh[4];
#pragma unroll
            for (int ks = 0; ks < 4; ++ks) {
                bw[ks] = *(const bf16x8*)&sB[buf][((nf2 * 3 + 0) * 4 + ks) * 512 + lane * 8];
                bs[ks] = *(const bf16x8*)&sB[buf][((nf2 * 3 + 1) * 4 + ks) * 512 + lane * 8];
                bh[ks] = *(const bf16x8*)&sB[buf][((nf2 * 3 + 2) * 4 + ks) * 512 + lane * 8];
            }
#pragma unroll
            for (int ks = 0; ks < 4; ++ks) {
#pragma unroll
                for (int mf = 0; mf < 2; ++mf) {
                    hA[mf][nf] = __builtin_amdgcn_mfma_f32_16x16x32_bf16(ax[mf][ks], bw[ks], hA[mf][nf], 0, 0, 0);
                    sA[mf][nf] = __builtin_amdgcn_mfma_f32_16x16x32_bf16(al[mf][ks], bs[ks], sA[mf][nf], 0, 0, 0);
                    fA[mf][nf] = __builtin_amdgcn_mfma_f32_16x16x32_bf16(al[mf][ks], bh[ks], fA[mf][nf], 0, 0, 0);
                }
            }
        }

        // epilogue for this 64-col chunk once both halves are done
        if (p & 1) {
            float be[4], b1[4], b2[4];
#pragma unroll
            for (int nf = 0; nf < 4; ++nf) {
                const int col = nc * 64 + nf * 16 + lrow;
                be[nf] = bE[col]; b1[nf] = blE[col]; b2[nf] = blE[256 + col];
            }
#pragma unroll
            for (int mf = 0; mf < 2; ++mf)
#pragma unroll
            for (int rr = 0; rr < 4; ++rr) {
                const int row = w * 32 + mf * 16 + lgrp * 4 + rr;
                if (row < rows) {
                    float* orow = out + (size_t)tokq[mf][rr] * OUTF;
                    const float wgt = wgtq[mf][rr];
#pragma unroll
                    for (int nf = 0; nf < 4; ++nf) {
                        const int col = nc * 64 + nf * 16 + lrow;
                        const float hv = hA[mf][nf][rr] + be[nf];
                        const float sc = sA[mf][nf][rr] + b1[nf];
                        const float sh = fA[mf][nf][rr] + b2[nf];
                        float val = wgt * __sinf(OMEGA_ * hv * sc + sh);
                        if (ACC) {
                            val += oldv[mf][rr][nf];
                            __builtin_nontemporal_store(val, &orow[col]);
                        } else {
                            orow[col] = val;
                        }
                    }
                }
            }
        }

        __syncthreads();   // drains stage vmcnt + lds reads; next buffer ready
    }
}

extern "C" void kernel_launch(void* const* d_in, const int* in_sizes, int n_in,
                              void* d_out, int out_size, void* d_ws, size_t ws_size,
                              hipStream_t stream)
{
    const float* x   = (const float*)d_in[0];
    const float* lat = (const float*)d_in[1];
    const float* gw  = (const float*)d_in[2];
    const float* gb  = (const float*)d_in[3];
    const float* W   = (const float*)d_in[4];
    const float* b   = (const float*)d_in[5];
    const float* Wl  = (const float*)d_in[6];
    const float* bl  = (const float*)d_in[7];
    float* out = (float*)d_out;
    const int N = in_sizes[0] / INF_;   // 131072

    char* ws = (char*)d_ws;
    unsigned int*   cnt  = (unsigned int*)ws;                          // [0..15]cnt [16..31]offs [32..47]cur
    unsigned short* eidx = (unsigned short*)(ws + 256);                // N
    float2*         gwt  = (float2*)(ws + 256 + 2 * (size_t)N);        // N
    unsigned int*   perm = (unsigned int*)(ws + 256 + 10 * (size_t)N); // 2N
    float*          wlst = (float*)(ws + 256 + 18 * (size_t)N);        // 2N
    unsigned short* Bpk  = (unsigned short*)(ws + 256 + 26 * (size_t)N); // 1.5MB

    (void)hipMemsetAsync(cnt, 0, 64, stream);

    pack_kernel<<<dim3(PACK_THREADS / 256), 256, 0, stream>>>(W, Wl, Bpk);
    gate_kernel<<<dim3(N / 256), 256, 0, stream>>>(x, lat, gw, gb, eidx, gwt, cnt,
                                                   out + (size_t)N * OUTF);
    scan_kernel<<<1, 64, 0, stream>>>(cnt);
    scatter_kernel<<<dim3(N / 256), 256, 0, stream>>>(eidx, gwt, cnt + 32, perm, wlst, N);

    const dim3 ggrid(NEXP, (N + 127) / 128);
    moe_gemm_kernel<false><<<ggrid, 256, 0, stream>>>(x, lat, Bpk, b, bl,
                                                      cnt, cnt + 16, perm, wlst, out, 0, N);
    moe_gemm_kernel<true ><<<ggrid, 256, 0, stream>>>(x, lat, Bpk, b, bl,
                                                      cnt, cnt + 16, perm, wlst, out, 1, N);
}